// Round 1
// baseline (478.935 us; speedup 1.0000x reference)
//
#include <hip/hip_runtime.h>
#include <hip/hip_bf16.h>
#include <stdint.h>

#define CDIM 256
#define HWSZ 1024           // 32*32 spatial per batch
#define RES_ELEMS 8388608   // 32*256*32*32
#define LOSS_IDX 8388608
#define IDX_BASE 8388609

// ---------------------------------------------------------------------------
// K0: per-code squared norms e2[k] = sum_c emb[k][c]^2 ; also zero loss slot.
// ---------------------------------------------------------------------------
__global__ void k0_prep(const float* __restrict__ emb, float* __restrict__ e2,
                        float* __restrict__ out_loss) {
    __shared__ float red[256];
    int t = threadIdx.x;
    int row = blockIdx.x * 64 + (t >> 2);
    int g = t & 3;
    const float* rp = emb + row * CDIM + g * 64;
    float s = 0.f;
    #pragma unroll 8
    for (int i = 0; i < 64; ++i) { float v = rp[i]; s += v * v; }
    red[t] = s;
    __syncthreads();
    if (g == 0) {
        e2[row] = red[t] + red[t + 1] + red[t + 2] + red[t + 3];
    }
    if (blockIdx.x == 0 && t == 0) out_loss[0] = 0.f;  // re-zero every call
}

// ---------------------------------------------------------------------------
// K2: fused distance + argmin. Block = 64 queries x all 1024 codes.
//  - z tile [64 q][256 c] staged coalesced (hw contiguous for fixed (b,c))
//  - e staged transposed [16 c][128 k] (stride 132 -> conflict-free b32 reads)
//  - thread computes 8 q x 4 k dot-products; d' = e2[k] - 2*dot (z2 constant
//    per query, irrelevant for argmin)
//  - full-precision fp32 argmin per thread, u64 (key<<32|k) LDS atomicMin
//    merge: ties resolve to smallest k, matching np.argmin.
// ---------------------------------------------------------------------------
__global__ __launch_bounds__(256, 2) void k2_argmin(
    const float* __restrict__ z_e, const float* __restrict__ emb,
    const float* __restrict__ e2g, int* __restrict__ win_out,
    float* __restrict__ out) {
    __shared__ float zt[64 * 258];            // [q][c] stride 258 (even -> b64 ok)
    __shared__ float esub[16 * 132];          // [c][k] stride 132
    __shared__ unsigned long long win[64];
    int t = threadIdx.x;
    int qbase = blockIdx.x * 64;
    int b = qbase >> 10;
    int hw0 = qbase & 1023;
    const float* zb = z_e + b * (CDIM * HWSZ) + hw0;

    {   // stage z tile: iteration i loads 4 c-rows of 64 contiguous floats
        int j = t & 63;
        int chi = t >> 6;
        #pragma unroll 4
        for (int i = 0; i < 64; ++i) {
            int c = i * 4 + chi;
            zt[j * 258 + c] = zb[c * HWSZ + j];
        }
    }
    if (t < 64) win[t] = ~0ull;
    __syncthreads();

    int tx = t & 31;       // code lane: k = kbase + tx + 32*s
    int ty = t >> 5;       // query group: q = ty + 8*r (lanes 0-31 of a wave
                           //  share ty -> z reads are wave-broadcast)
    float m1d[8];
    int   m1k[8];
    #pragma unroll
    for (int r = 0; r < 8; ++r) { m1d[r] = 3.4e38f; m1k[r] = 0; }

    for (int kc = 0; kc < 8; ++kc) {
        int kbase = kc * 128;
        float acc[8][4];
        #pragma unroll
        for (int r = 0; r < 8; ++r)
            #pragma unroll
            for (int s = 0; s < 4; ++s) acc[r][s] = 0.f;

        for (int cc = 0; cc < 16; ++cc) {
            int cbase = cc * 16;
            {   // stage esub[c][k] <- emb[kbase+k][cbase+c]; 2-way (free) banks
                int c = t & 15;
                int k0 = t >> 4;
                #pragma unroll
                for (int i = 0; i < 8; ++i) {
                    int k = i * 16 + k0;
                    esub[c * 132 + k] = emb[(kbase + k) * CDIM + cbase + c];
                }
            }
            __syncthreads();
            #pragma unroll
            for (int c2 = 0; c2 < 8; ++c2) {
                float2 zq[8];
                #pragma unroll
                for (int r = 0; r < 8; ++r)
                    zq[r] = *(const float2*)&zt[(ty + 8 * r) * 258 + cbase + 2 * c2];
                float ev0[4], ev1[4];
                #pragma unroll
                for (int s = 0; s < 4; ++s) {
                    ev0[s] = esub[(2 * c2) * 132 + tx + 32 * s];
                    ev1[s] = esub[(2 * c2 + 1) * 132 + tx + 32 * s];
                }
                #pragma unroll
                for (int r = 0; r < 8; ++r)
                    #pragma unroll
                    for (int s = 0; s < 4; ++s)
                        acc[r][s] = fmaf(zq[r].x, ev0[s],
                                    fmaf(zq[r].y, ev1[s], acc[r][s]));
            }
            __syncthreads();
        }
        // epilogue: d' = e2 - 2*dot, exact fp32 running argmin
        #pragma unroll
        for (int s = 0; s < 4; ++s) {
            int k = kbase + tx + 32 * s;
            float e2k = e2g[k];
            #pragma unroll
            for (int r = 0; r < 8; ++r) {
                float d = fmaf(-2.f, acc[r][s], e2k);
                if (d < m1d[r]) { m1d[r] = d; m1k[r] = k; }
            }
        }
    }

    // cross-thread merge per query (monotone float key, index in low bits)
    #pragma unroll
    for (int r = 0; r < 8; ++r) {
        int q = ty + 8 * r;
        unsigned u = __float_as_uint(m1d[r]);
        unsigned key = u ^ ((unsigned)(((int)u) >> 31) | 0x80000000u);
        unsigned long long p =
            ((unsigned long long)key << 32) | (unsigned)m1k[r];
        atomicMin(&win[q], p);
    }
    __syncthreads();
    if (t < 64) {
        int kstar = (int)(win[t] & 0xFFFFFFFFull);
        win_out[qbase + t] = kstar;
        out[IDX_BASE + qbase + t] = (float)kstar;  // indices as float32
    }
}

// ---------------------------------------------------------------------------
// K3: res = emb[k*] scattered back to (b,c,h,w) + fused codebook loss.
// ---------------------------------------------------------------------------
__global__ __launch_bounds__(256, 2) void k3_output(
    const float* __restrict__ z_e, const float* __restrict__ emb,
    const int* __restrict__ win_in, float* __restrict__ out) {
    __shared__ float lde[64 * 257];
    __shared__ int lwin[64];
    __shared__ float lred[4];
    int t = threadIdx.x;
    int qbase = blockIdx.x * 64;
    int b = qbase >> 10;
    int hw0 = qbase & 1023;
    if (t < 64) lwin[t] = win_in[qbase + t];
    __syncthreads();
    for (int i = 0; i < 64; ++i) {          // coalesced 1KB row loads
        lde[i * 257 + t] = emb[lwin[i] * CDIM + t];
    }
    __syncthreads();
    const float* zb = z_e + b * (CDIM * HWSZ) + hw0;
    float* rb = out + b * (CDIM * HWSZ) + hw0;
    int j = t & 63;
    int chi = t >> 6;
    float lsum = 0.f;
    #pragma unroll 4
    for (int p = 0; p < 64; ++p) {
        int c = p * 4 + chi;
        float v = lde[j * 257 + c];         // banks (j+c)%32 -> 2-way, free
        float zv = zb[c * HWSZ + j];
        rb[c * HWSZ + j] = v;
        float d = v - zv;
        lsum = fmaf(d, d, lsum);
    }
    #pragma unroll
    for (int off = 32; off > 0; off >>= 1)
        lsum += __shfl_down(lsum, off, 64);
    int lane = t & 63;
    int w = t >> 6;
    if (lane == 0) lred[w] = lsum;
    __syncthreads();
    if (t == 0) {
        float tot = lred[0] + lred[1] + lred[2] + lred[3];
        atomicAdd(&out[LOSS_IDX], tot * (1.25f / 8388608.f));
    }
}

// ---------------------------------------------------------------------------
extern "C" void kernel_launch(void* const* d_in, const int* in_sizes, int n_in,
                              void* d_out, int out_size, void* d_ws, size_t ws_size,
                              hipStream_t stream) {
    const float* z_e = (const float*)d_in[0];   // (32,256,32,32) fp32
    const float* emb = (const float*)d_in[1];   // (1024,256) fp32
    float* out = (float*)d_out;                 // res | loss | indices (float)
    int*   win = (int*)d_ws;                            // 32768 winner indices
    float* e2  = (float*)((char*)d_ws + 32768 * 4);     // 1024 code norms

    k0_prep  <<<16,  256, 0, stream>>>(emb, e2, out + LOSS_IDX);
    k2_argmin<<<512, 256, 0, stream>>>(z_e, emb, e2, win, out);
    k3_output<<<512, 256, 0, stream>>>(z_e, emb, win, out);
}

// Round 2
// 153.572 us; speedup vs baseline: 3.1186x; 3.1186x over previous
//
#include <hip/hip_runtime.h>
#include <hip/hip_bf16.h>
#include <hip/hip_fp16.h>
#include <stdint.h>

#define LOSS_IDX 8388608
#define IDX_BASE 8388609

typedef _Float16 half8 __attribute__((ext_vector_type(8)));
typedef float f32x4 __attribute__((ext_vector_type(4)));
typedef unsigned long long u64;

// ---- workspace layout (bytes) ----
#define WIN_OFF   0            // 32768 * 8  winner (key<<32 | k)
#define E2_OFF    262144       // 1024 * 4   code norms
#define ETILE_OFF 266240       // 16 images * 81920 B  pre-tiled fp16 hi/lo emb
// image (cg,cc): [hi: 512 rows * 80 B][lo: 512 rows * 80 B]; row = 32 c halfs + pad

static __device__ __forceinline__ unsigned fkey(float d) {
    unsigned u = __float_as_uint(d);
    return u ^ ((unsigned)(((int)u) >> 31) | 0x80000000u);
}

// ---------------------------------------------------------------------------
// K0: e2 norms, emb -> pre-tiled fp16 hi/lo planes, winner-table init, loss=0.
// One wave per code row. 256 blocks x 256 threads = 65536 threads.
// ---------------------------------------------------------------------------
__global__ __launch_bounds__(256) void k0_prep(
    const float* __restrict__ emb, float* __restrict__ e2,
    ushort* __restrict__ etile, unsigned* __restrict__ win32,
    float* __restrict__ out) {
    int tid = blockIdx.x * 256 + threadIdx.x;      // 0..65535
    win32[tid] = 0xFFFFFFFFu;                      // win64 = all-ones
    if (tid == 0) out[LOSS_IDX] = 0.f;             // re-zero every call
    int code = tid >> 6;
    int lane = tid & 63;
    const float4 v4 = *(const float4*)&emb[code * 256 + lane * 4];
    float vv[4] = {v4.x, v4.y, v4.z, v4.w};
    float s = vv[0]*vv[0] + vv[1]*vv[1] + vv[2]*vv[2] + vv[3]*vv[3];
    #pragma unroll
    for (int off = 32; off > 0; off >>= 1) s += __shfl_down(s, off, 64);
    if (lane == 0) e2[code] = s;
    int cg = code >> 9, n = code & 511;
    #pragma unroll
    for (int i = 0; i < 4; ++i) {
        int c = lane * 4 + i;
        float v = vv[i];
        __half h = __float2half(v);                       // RNE
        __half l = __float2half(v - __half2float(h));     // residual
        int cc = c >> 5, cw = c & 31;
        int hoff = (cg * 8 + cc) * 40960 + n * 40 + (cw >> 3) * 8 + (cw & 7);
        etile[hoff] = __half_as_ushort(h);                // hi plane
        etile[hoff + 20480] = __half_as_ushort(l);        // lo plane
    }
}

// ---------------------------------------------------------------------------
// K2: fp16x3 MFMA distance GEMM + fused argmin.
// Block: 512 thr (8 waves), tile 128 q x 512 codes, contraction 256 in 8x32.
//  - z: transpose+split staged to LDS (XOR chunk swizzle -> conflict-free)
//  - e: global_load_lds(16B) from pre-tiled image (80 B rows, conflict-free)
//  - dot = zh*eh + zh*el + zl*eh (3 MFMA per 16x16x32 tile)
//  - epilogue: d' = e2 - 2 dot, packed-u64 shuffle argmin, global atomicMin
//  - sum(z^2) accumulated during staging (loss part 1, cg==0 blocks only)
// ---------------------------------------------------------------------------
__global__ __launch_bounds__(512, 2) void k2_mfma(
    const float* __restrict__ z_e, const float* __restrict__ e2g,
    const ushort* __restrict__ etile, u64* __restrict__ win64,
    float* __restrict__ out) {
    __shared__ __attribute__((aligned(16))) ushort zh_s[128 * 40];
    __shared__ __attribute__((aligned(16))) ushort zl_s[128 * 40];
    __shared__ __attribute__((aligned(16))) ushort ehl_s[2 * 512 * 40];
    __shared__ float e2_s[512];
    __shared__ float red_s[8];

    int t = threadIdx.x;
    int lane = t & 63;
    int w = t >> 6;
    int cg = blockIdx.x & 1;        // code group: 512 codes
    int qg = blockIdx.x >> 1;       // query group: 128 queries
    int qbase = qg * 128;
    int b = qbase >> 10;
    int hw0 = qbase & 1023;
    const float* zb = z_e + b * (256 * 1024) + hw0;

    e2_s[t & 511] = e2g[cg * 512 + (t & 511)];

    f32x4 acc[4][8];
    #pragma unroll
    for (int mt = 0; mt < 4; ++mt)
        #pragma unroll
        for (int nt = 0; nt < 8; ++nt) acc[mt][nt] = (f32x4){0.f, 0.f, 0.f, 0.f};

    int qz = t & 127, sz = t >> 7;  // staging: q fixed per thread, 4 c-slots
    float z2acc = 0.f;
    int qh = w >> 2, nqr = w & 3;   // wave tile: 64 q x 128 codes
    int lm = lane & 15, kq = lane >> 4;

    for (int cc = 0; cc < 8; ++cc) {
        __syncthreads();
        // ---- stage e chunk: 81920 B contiguous DMA ----
        const char* gsrc = (const char*)(etile + (size_t)(cg * 8 + cc) * 40960);
        #pragma unroll
        for (int i = 0; i < 10; ++i) {
            int off = (i * 512 + t) * 16;
            __builtin_amdgcn_global_load_lds(
                (const __attribute__((address_space(1))) unsigned int*)(gsrc + off),
                (__attribute__((address_space(3))) unsigned int*)((char*)ehl_s + off),
                16, 0, 0);
        }
        // ---- stage z chunk: transpose + hi/lo split ----
        int cbase = cc * 32;
        #pragma unroll
        for (int i = 0; i < 4; ++i) {
            int c2v = i * 4 + sz;               // b32 slot 0..15
            int c = cbase + 2 * c2v;
            float v0 = zb[c * 1024 + qz];
            float v1 = zb[(c + 1) * 1024 + qz];
            z2acc = fmaf(v0, v0, z2acc);
            z2acc = fmaf(v1, v1, z2acc);
            __half h0 = __float2half(v0), h1 = __float2half(v1);
            __half l0 = __float2half(v0 - __half2float(h0));
            __half l1 = __float2half(v1 - __half2float(h1));
            unsigned wh = (unsigned)__half_as_ushort(h0) | ((unsigned)__half_as_ushort(h1) << 16);
            unsigned wl = (unsigned)__half_as_ushort(l0) | ((unsigned)__half_as_ushort(l1) << 16);
            int ch = (c2v >> 2) ^ ((qz >> 3) & 3);     // chunk XOR swizzle
            int idx = qz * 20 + ch * 4 + (c2v & 3);
            ((unsigned*)zh_s)[idx] = wh;
            ((unsigned*)zl_s)[idx] = wl;
        }
        __syncthreads();
        // ---- compute: one 32-c k-step ----
        half8 ah[4], al[4];
        #pragma unroll
        for (int mt = 0; mt < 4; ++mt) {
            int q = qh * 64 + mt * 16 + lm;
            int ch = kq ^ ((q >> 3) & 3);
            ah[mt] = *(const half8*)&zh_s[q * 40 + ch * 8];
            al[mt] = *(const half8*)&zl_s[q * 40 + ch * 8];
        }
        #pragma unroll
        for (int nt = 0; nt < 8; ++nt) {
            int n = nqr * 128 + nt * 16 + lm;
            half8 bh = *(const half8*)&ehl_s[n * 40 + kq * 8];
            half8 bl = *(const half8*)&ehl_s[20480 + n * 40 + kq * 8];
            #pragma unroll
            for (int mt = 0; mt < 4; ++mt) {
                acc[mt][nt] = __builtin_amdgcn_mfma_f32_16x16x32_f16(ah[mt], bh, acc[mt][nt], 0, 0, 0);
                acc[mt][nt] = __builtin_amdgcn_mfma_f32_16x16x32_f16(ah[mt], bl, acc[mt][nt], 0, 0, 0);
                acc[mt][nt] = __builtin_amdgcn_mfma_f32_16x16x32_f16(al[mt], bh, acc[mt][nt], 0, 0, 0);
            }
        }
    }

    // ---- argmin epilogue: C layout col=lane&15 (code), row=(lane>>4)*4+r (q)
    int lg = lane >> 4;
    #pragma unroll
    for (int mt = 0; mt < 4; ++mt)
        #pragma unroll
        for (int r = 0; r < 4; ++r) {
            int qloc = qh * 64 + mt * 16 + lg * 4 + r;
            u64 best = ~0ull;
            #pragma unroll
            for (int nt = 0; nt < 8; ++nt) {
                int nloc = nqr * 128 + nt * 16 + lm;
                float d = fmaf(-2.f, acc[mt][nt][r], e2_s[nloc]);
                u64 p = ((u64)fkey(d) << 32) | (unsigned)(cg * 512 + nloc);
                if (p < best) best = p;
            }
            #pragma unroll
            for (int m = 1; m <= 8; m <<= 1) {     // reduce over 16 code-lanes
                unsigned blo = __shfl_xor((unsigned)best, m, 64);
                unsigned bhi = __shfl_xor((unsigned)(best >> 32), m, 64);
                u64 p = ((u64)bhi << 32) | blo;
                if (p < best) best = p;
            }
            if (lm == 0) atomicMin(&win64[qbase + qloc], best);
        }

    // ---- sum(z^2) loss contribution (count once: cg==0 blocks) ----
    #pragma unroll
    for (int off = 32; off > 0; off >>= 1) z2acc += __shfl_down(z2acc, off, 64);
    if (lane == 0) red_s[w] = z2acc;
    __syncthreads();
    if (t == 0 && cg == 0) {
        float s = 0.f;
        #pragma unroll
        for (int i = 0; i < 8; ++i) s += red_s[i];
        atomicAdd(&out[LOSS_IDX], s * (1.25f / 8388608.f));
    }
}

// ---------------------------------------------------------------------------
// K3: res = emb[k*] scattered to (b,c,h,w); indices as float; loss part 2
// recovered from the winner key (d'win = e2 - 2 z.e = (zq-z)^2 - z^2).
// ---------------------------------------------------------------------------
__global__ __launch_bounds__(256, 2) void k3_out(
    const float* __restrict__ emb, const u64* __restrict__ win64,
    float* __restrict__ out) {
    __shared__ float lde[64 * 257];
    __shared__ int lwin[64];
    int t = threadIdx.x;
    int qbase = blockIdx.x * 64;
    int b = qbase >> 10;
    int hw0 = qbase & 1023;
    if (t < 64) {                                  // wave 0 only (uniform)
        u64 p = win64[qbase + t];
        int k = (int)(p & 0xFFFFFFFFull);
        lwin[t] = k;
        out[IDX_BASE + qbase + t] = (float)k;
        unsigned key = (unsigned)(p >> 32);
        unsigned u = (key & 0x80000000u) ? (key ^ 0x80000000u) : ~key;
        float dval = __uint_as_float(u);
        #pragma unroll
        for (int off = 32; off > 0; off >>= 1) dval += __shfl_down(dval, off, 64);
        if (t == 0) atomicAdd(&out[LOSS_IDX], dval * (1.25f / 8388608.f));
    }
    __syncthreads();
    for (int i = 0; i < 64; ++i)                   // coalesced 1 KB row loads
        lde[i * 257 + t] = emb[lwin[i] * 256 + t];
    __syncthreads();
    float* rb = out + b * (256 * 1024) + hw0;
    int j = t & 63, chi = t >> 6;
    #pragma unroll 4
    for (int p = 0; p < 64; ++p) {
        int c = p * 4 + chi;
        rb[c * 1024 + j] = lde[j * 257 + c];       // 2-way banks (free)
    }
}

// ---------------------------------------------------------------------------
extern "C" void kernel_launch(void* const* d_in, const int* in_sizes, int n_in,
                              void* d_out, int out_size, void* d_ws, size_t ws_size,
                              hipStream_t stream) {
    const float* z_e = (const float*)d_in[0];   // (32,256,32,32) fp32
    const float* emb = (const float*)d_in[1];   // (1024,256) fp32
    float* out = (float*)d_out;                 // res | loss | indices(float)
    u64*    win   = (u64*)((char*)d_ws + WIN_OFF);
    float*  e2    = (float*)((char*)d_ws + E2_OFF);
    ushort* etile = (ushort*)((char*)d_ws + ETILE_OFF);

    k0_prep<<<256, 256, 0, stream>>>(emb, e2, etile, (unsigned*)win, out);
    k2_mfma<<<512, 512, 0, stream>>>(z_e, e2, etile, win, out);
    k3_out <<<512, 256, 0, stream>>>(emb, win, out);
}